// Round 13
// baseline (110.040 us; speedup 1.0000x reference)
//
#include <hip/hip_runtime.h>
#include <cstdint>
#include <cmath>

#define B_ROWS 256
#define V_COLS 128000
#define CHUNKS 25
#define CHUNK_QUADS 1280           // V_COLS/4/CHUNKS; exactly 5 quads/thread
#define ATHREADS 256
#define AWAVES 4
#define QPT 5
#define LOG2E 1.4426950408889634f
// gumbel range: u in [tiny, 1-2^-24] -> g in [-4.47, 16.64], window ~20.4 in
// sx units. Screen margin 21.2 > 20.4: sx <= M-21.2 can never win. Applied at
// chunk level (vs chunk max) and wave-quad level (vs quad max), both exact.
#define GUMBEL_WINDOW 21.2f

// ws float layout:
//  G region: [row][chunk][4] = (Av, Ai, Mc, Sc)  @ 0,      25600 floats
//  S region: [row][chunk][2] = (Gv, Gi)          @ 25600,  12800 floats
#define G_STRIDE 4
#define S_OFF (B_ROWS * CHUNKS * G_STRIDE)

__device__ __forceinline__ uint32_t rotl32(uint32_t x, uint32_t d) {
  return __builtin_amdgcn_alignbit(x, x, 32u - d);
}

// threefry2x32 key (0,42), XOR of outputs (JAX partitionable threefry).
// Caller pre-adds k1=42 into x1 (x0 = 0+k0 = 0): bit-identical stream.
__device__ __forceinline__ uint32_t threefry_xor_pre(uint32_t x1) {
  const uint32_t k1 = 42u;
  const uint32_t k2 = 0x1BD11BF0u;   // 0x1BD11BDA ^ 0 ^ 42
  uint32_t x0 = 0u;
#define TF_RND(r) { x0 += x1; x1 = rotl32(x1, (r)); x1 ^= x0; }
  TF_RND(13) TF_RND(15) TF_RND(26) TF_RND(6)
  x0 += k1; x1 += k2 + 1u;
  TF_RND(17) TF_RND(29) TF_RND(16) TF_RND(24)
  x0 += k2; x1 += 0u + 2u;
  TF_RND(13) TF_RND(15) TF_RND(26) TF_RND(6)
  x0 += 0u; x1 += k1 + 3u;
  TF_RND(17) TF_RND(29) TF_RND(16) TF_RND(24)
  x0 += k1; x1 += k2 + 4u;
  TF_RND(13) TF_RND(15) TF_RND(26) TF_RND(6)
  x0 += k2; x1 += 0u + 5u;
#undef TF_RND
  return x0 ^ x1;
}

// ll2 = log2(-log2(u)); rank candidate c = fmaf(x, inv_t*log2e, -ll2),
// a positive per-row affine map of the true gumbel+sx (argmax-equivalent).
__device__ __forceinline__ float gumbel_ll2(uint32_t bits) {
  uint32_t ub = (bits >> 9) | 0x3f800000u;
  float f = __uint_as_float(ub) - 1.0f;
  float u = fmaxf(f, 1.17549435e-38f);
  return __log2f(-__log2f(u));
}

// ---------- K1: softmax (Mc,Sc) + greedy argmax partials (no RNG) ----------
__global__ __launch_bounds__(ATHREADS) void pass1_kernel(
    const float* __restrict__ logits,
    const float* __restrict__ temps,
    float* __restrict__ ws) {
  const uint32_t bx = blockIdx.x;
  const uint32_t b = bx / CHUNKS;
  const uint32_t chunk = bx - b * CHUNKS;
  const int tid = threadIdx.x;
  const float t = temps[b];
  const float inv_t = (t == 0.0f) ? 1.0f : (1.0f / t);
  const float* __restrict__ row = logits + (size_t)b * V_COLS;
  const int q0 = (int)chunk * CHUNK_QUADS + tid;

  float4 xq[QPT];
#pragma unroll
  for (int j = 0; j < QPT; ++j)
    xq[j] = reinterpret_cast<const float4*>(row)[q0 + j * ATHREADS];

  // greedy argmax over raw x; strict > + ascending order => first index wins
  float av = -INFINITY; int ai = 0;
  const int v0 = q0 * 4;
#pragma unroll
  for (int j = 0; j < QPT; ++j) {
    const float xa[4] = {xq[j].x, xq[j].y, xq[j].z, xq[j].w};
#pragma unroll
    for (int k = 0; k < 4; ++k) {
      const bool up = xa[k] > av;
      av = up ? xa[k] : av;
      ai = up ? (v0 + j * 1024 + k) : ai;
    }
  }

  // thread max of sx bitwise (mul by inv_t>0 is round-monotone)
  const float mthr = av * inv_t;
  float s = 0.0f;
#pragma unroll
  for (int j = 0; j < QPT; ++j) {
    s += __expf(fmaf(xq[j].x, inv_t, -mthr));
    s += __expf(fmaf(xq[j].y, inv_t, -mthr));
    s += __expf(fmaf(xq[j].z, inv_t, -mthr));
    s += __expf(fmaf(xq[j].w, inv_t, -mthr));
  }

  float m = mthr;
#pragma unroll
  for (int off = 32; off > 0; off >>= 1) {
    float ov = __shfl_xor(av, off);
    int   oi = __shfl_xor(ai, off);
    if (ov > av || (ov == av && oi < ai)) { av = ov; ai = oi; }
    float om = __shfl_xor(m, off);
    float os = __shfl_xor(s, off);
    float mn = fmaxf(m, om);
    s = fmaf(s, __expf(m - mn), os * __expf(om - mn));
    m = mn;
  }

  __shared__ float lds_av[AWAVES]; __shared__ int lds_ai[AWAVES];
  __shared__ float lds_m[AWAVES];  __shared__ float lds_s[AWAVES];
  const int wid = tid >> 6;
  if ((tid & 63) == 0) {
    lds_av[wid] = av; lds_ai[wid] = ai;
    lds_m[wid] = m;   lds_s[wid] = s;
  }
  __syncthreads();
  if (tid == 0) {
    float Av = lds_av[0]; int Ai = lds_ai[0];
    float M = lds_m[0];   float S = lds_s[0];
#pragma unroll
    for (int w = 1; w < AWAVES; ++w) {
      float ov = lds_av[w]; int oi = lds_ai[w];
      if (ov > Av || (ov == Av && oi < Ai)) { Av = ov; Ai = oi; }
      float om = lds_m[w]; float os = lds_s[w];
      float mn = fmaxf(M, om);
      S = fmaf(S, __expf(M - mn), os * __expf(om - mn));
      M = mn;
    }
    float* p = ws + (size_t)(b * CHUNKS + chunk) * G_STRIDE;
    p[0] = Av; p[1] = __int_as_float(Ai);
    p[2] = M;  p[3] = S;
  }
}

// ---------- K2: self-merge + fused probs + screened gumbel ----------
__global__ __launch_bounds__(ATHREADS) void pass2_kernel(
    const float* __restrict__ logits,
    const float* __restrict__ temps,
    float* __restrict__ ws,
    float* __restrict__ out) {
  const uint32_t bx = blockIdx.x;
  const uint32_t b = bx / CHUNKS;
  const uint32_t chunk = bx - b * CHUNKS;
  const int tid = threadIdx.x;
  const float t = temps[b];
  const float inv_t = (t == 0.0f) ? 1.0f : (1.0f / t);

  // merge this row's 25 chunk partials (uniform across threads/blocks)
  const float* gp = ws + (size_t)b * CHUNKS * G_STRIDE;
  float M = -INFINITY, S = 0.0f;
#pragma unroll
  for (int c = 0; c < CHUNKS; ++c) {
    const float om = gp[c * G_STRIDE + 2];
    const float os = gp[c * G_STRIDE + 3];
    const float mn = fmaxf(M, om);
    S = fmaf(S, __expf(M - mn), os * __expf(om - mn));
    M = mn;
  }
  const float invS = 1.0f / S;
  const float cexp = __logf(invS) - M;   // probs = exp(fmaf(x, inv_t, cexp))
  const float a = inv_t * LOG2E;          // gumbel rank scale (per-row, >0)
  const float myM = gp[chunk * G_STRIDE + 2];   // this chunk's max sx
  const float thrM = M - GUMBEL_WINDOW;

  const float* __restrict__ row = logits + (size_t)b * V_COLS;
  float* __restrict__ prow = out + B_ROWS + (size_t)b * V_COLS;
  const int q0 = (int)chunk * CHUNK_QUADS + tid;
  const int v0 = q0 * 4;
  const uint32_t cb42 = b * (uint32_t)V_COLS + (uint32_t)v0 + 42u;

  // block-uniform: skip gumbel if t==0 or whole chunk below the exact bound
  const bool doG = (t != 0.0f) && (myM > thrM);

  if (doG) {
    float gv = -INFINITY; int gi = 0;
#pragma unroll
    for (int j = 0; j < QPT; ++j) {
      const float4 x4 = reinterpret_cast<const float4*>(row)[q0 + j * ATHREADS];
      float4 p4;
      p4.x = __expf(fmaf(x4.x, inv_t, cexp));
      p4.y = __expf(fmaf(x4.y, inv_t, cexp));
      p4.z = __expf(fmaf(x4.z, inv_t, cexp));
      p4.w = __expf(fmaf(x4.w, inv_t, cexp));
      reinterpret_cast<float4*>(prow)[q0 + j * ATHREADS] = p4;
      const float xa[4] = {x4.x, x4.y, x4.z, x4.w};
      const float mx4 = fmaxf(fmaxf(xa[0], xa[1]), fmaxf(xa[2], xa[3]));
      if (__any(mx4 * inv_t > thrM)) {
#pragma unroll
        for (int k = 0; k < 4; ++k) {
          const float ll2 =
              gumbel_ll2(threefry_xor_pre(cb42 + (uint32_t)(j * 1024 + k)));
          const float c = fmaf(xa[k], a, -ll2);
          const bool up = c > gv;
          gv = up ? c : gv;
          gi = up ? (v0 + j * 1024 + k) : gi;
        }
      }
    }

#pragma unroll
    for (int off = 32; off > 0; off >>= 1) {
      float ov = __shfl_xor(gv, off);
      int   oi = __shfl_xor(gi, off);
      if (ov > gv || (ov == gv && oi < gi)) { gv = ov; gi = oi; }
    }

    __shared__ float lds_gv[AWAVES]; __shared__ int lds_gi[AWAVES];
    const int wid = tid >> 6;
    if ((tid & 63) == 0) { lds_gv[wid] = gv; lds_gi[wid] = gi; }
    __syncthreads();
    if (tid == 0) {
      float Gv = lds_gv[0]; int Gi = lds_gi[0];
#pragma unroll
      for (int w = 1; w < AWAVES; ++w) {
        float ov = lds_gv[w]; int oi = lds_gi[w];
        if (ov > Gv || (ov == Gv && oi < Gi)) { Gv = ov; Gi = oi; }
      }
      float* p = ws + S_OFF + (size_t)(b * CHUNKS + chunk) * 2;
      p[0] = Gv; p[1] = __int_as_float(Gi);
    }
  } else {
    // probs only (t==0 row, or chunk provably can't win the gumbel race)
#pragma unroll
    for (int j = 0; j < QPT; ++j) {
      const float4 x4 = reinterpret_cast<const float4*>(row)[q0 + j * ATHREADS];
      float4 p4;
      p4.x = __expf(fmaf(x4.x, inv_t, cexp));
      p4.y = __expf(fmaf(x4.y, inv_t, cexp));
      p4.z = __expf(fmaf(x4.z, inv_t, cexp));
      p4.w = __expf(fmaf(x4.w, inv_t, cexp));
      reinterpret_cast<float4*>(prow)[q0 + j * ATHREADS] = p4;
    }
    if (t != 0.0f && tid == 0) {
      // sentinel so fin merge never reads poisoned ws
      float* p = ws + S_OFF + (size_t)(b * CHUNKS + chunk) * 2;
      p[0] = -INFINITY; p[1] = __int_as_float(0);
    }
  }
}

// ---------- K3: merge partials -> tokens ----------
__global__ __launch_bounds__(B_ROWS) void fin2_kernel(
    const float* __restrict__ temps,
    const float* __restrict__ ws,
    float* __restrict__ out) {
  const int r = threadIdx.x;
  const float t = temps[r];
  int token;
  if (t == 0.0f) {
    const float* gp = ws + (size_t)r * CHUNKS * G_STRIDE;
    float Av = -INFINITY; int Ai = 0;
#pragma unroll
    for (int c = 0; c < CHUNKS; ++c) {
      float ov = gp[c * G_STRIDE]; int oi = __float_as_int(gp[c * G_STRIDE + 1]);
      if (ov > Av) { Av = ov; Ai = oi; }   // ascending: first index wins
    }
    token = Ai;
  } else {
    const float* sp = ws + S_OFF + (size_t)r * CHUNKS * 2;
    float Sv = -INFINITY; int Si = 0;
#pragma unroll
    for (int c = 0; c < CHUNKS; ++c) {
      float ov = sp[2 * c]; int oi = __float_as_int(sp[2 * c + 1]);
      if (ov > Sv) { Sv = ov; Si = oi; }   // ascending: first index wins
    }
    token = Si;
  }
  out[r] = (float)token;
}

extern "C" void kernel_launch(void* const* d_in, const int* in_sizes, int n_in,
                              void* d_out, int out_size, void* d_ws, size_t ws_size,
                              hipStream_t stream) {
  const float* logits = (const float*)d_in[0];
  const float* temps  = (const float*)d_in[1];
  float* out = (float*)d_out;
  float* ws  = (float*)d_ws;
  pass1_kernel<<<B_ROWS * CHUNKS, ATHREADS, 0, stream>>>(logits, temps, ws);
  pass2_kernel<<<B_ROWS * CHUNKS, ATHREADS, 0, stream>>>(logits, temps, ws, out);
  fin2_kernel<<<1, B_ROWS, 0, stream>>>(temps, ws, out);
}

// Round 14
// 102.089 us; speedup vs baseline: 1.0779x; 1.0779x over previous
//
#include <hip/hip_runtime.h>
#include <cstdint>
#include <cmath>

#define B_ROWS 256
#define V_COLS 128000
#define CHUNKS 25
#define CHUNK_QUADS 1280           // V_COLS/4/CHUNKS; exactly 5 quads/thread
#define ATHREADS 256
#define AWAVES 4
#define QPT 5
#define LOG2E 1.4426950408889634f
// gumbel span: u in [tiny, 1-2^-24] -> window ~20.4 sx-units. Chunk skip uses
// 21.2; per-quad screen threshold precomputed in raw-x units with margin 21.4
// (extra 0.2 absorbs the t*inv_t rounding round-trip). Both exact.
#define GUMBEL_WINDOW 21.2f
#define GUMBEL_WINDOW_X 21.4f

// ws float layout:
//  G region: [row][chunk][4] = (Av, Ai, Mc, Sc)            @ 0,     25600
//  FIN:      [row][8] = (cexp, a, thrX, Mrow, Ai, pad...)  @ 25600,  2048
//  S region: [row][chunk][2] = (Gv, Gi)                    @ 27648, 12800
#define G_STRIDE 4
#define FIN_OFF (B_ROWS * CHUNKS * G_STRIDE)
#define S_OFF (FIN_OFF + B_ROWS * 8)

__device__ __forceinline__ uint32_t rotl32(uint32_t x, uint32_t d) {
  return __builtin_amdgcn_alignbit(x, x, 32u - d);
}

// threefry2x32 key (0,42), XOR of outputs (JAX partitionable threefry).
// Caller pre-adds k1=42 into x1 (x0 = 0+k0 = 0): bit-identical stream.
__device__ __forceinline__ uint32_t threefry_xor_pre(uint32_t x1) {
  const uint32_t k1 = 42u;
  const uint32_t k2 = 0x1BD11BF0u;   // 0x1BD11BDA ^ 0 ^ 42
  uint32_t x0 = 0u;
#define TF_RND(r) { x0 += x1; x1 = rotl32(x1, (r)); x1 ^= x0; }
  TF_RND(13) TF_RND(15) TF_RND(26) TF_RND(6)
  x0 += k1; x1 += k2 + 1u;
  TF_RND(17) TF_RND(29) TF_RND(16) TF_RND(24)
  x0 += k2; x1 += 0u + 2u;
  TF_RND(13) TF_RND(15) TF_RND(26) TF_RND(6)
  x0 += 0u; x1 += k1 + 3u;
  TF_RND(17) TF_RND(29) TF_RND(16) TF_RND(24)
  x0 += k1; x1 += k2 + 4u;
  TF_RND(13) TF_RND(15) TF_RND(26) TF_RND(6)
  x0 += k2; x1 += 0u + 5u;
#undef TF_RND
  return x0 ^ x1;
}

// ll2 = log2(-log2(u)); rank candidate c = fmaf(x, a, -ll2) with a = inv_t
// * log2e: positive per-row affine map of gumbel+sx => argmax-equivalent.
__device__ __forceinline__ float gumbel_ll2(uint32_t bits) {
  uint32_t ub = (bits >> 9) | 0x3f800000u;
  float f = __uint_as_float(ub) - 1.0f;
  float u = fmaxf(f, 1.17549435e-38f);
  return __log2f(-__log2f(u));
}

// ---------- K1: softmax (Mc,Sc) + greedy argmax partials (no RNG) ----------
__global__ __launch_bounds__(ATHREADS) void pass1_kernel(
    const float* __restrict__ logits,
    const float* __restrict__ temps,
    float* __restrict__ ws) {
  const uint32_t bx = blockIdx.x;
  const uint32_t b = bx / CHUNKS;
  const uint32_t chunk = bx - b * CHUNKS;
  const int tid = threadIdx.x;
  const float t = temps[b];
  const float inv_t = (t == 0.0f) ? 1.0f : (1.0f / t);
  const float* __restrict__ row = logits + (size_t)b * V_COLS;
  const int q0 = (int)chunk * CHUNK_QUADS + tid;

  float4 xq[QPT];
#pragma unroll
  for (int j = 0; j < QPT; ++j)
    xq[j] = reinterpret_cast<const float4*>(row)[q0 + j * ATHREADS];

  // greedy argmax over raw x; strict > + ascending order => first index wins
  float av = -INFINITY; int ai = 0;
  const int v0 = q0 * 4;
#pragma unroll
  for (int j = 0; j < QPT; ++j) {
    const float xa[4] = {xq[j].x, xq[j].y, xq[j].z, xq[j].w};
#pragma unroll
    for (int k = 0; k < 4; ++k) {
      const bool up = xa[k] > av;
      av = up ? xa[k] : av;
      ai = up ? (v0 + j * 1024 + k) : ai;
    }
  }

  // thread max of sx bitwise (mul by inv_t>0 is round-monotone)
  const float mthr = av * inv_t;
  float s = 0.0f;
#pragma unroll
  for (int j = 0; j < QPT; ++j) {
    s += __expf(fmaf(xq[j].x, inv_t, -mthr));
    s += __expf(fmaf(xq[j].y, inv_t, -mthr));
    s += __expf(fmaf(xq[j].z, inv_t, -mthr));
    s += __expf(fmaf(xq[j].w, inv_t, -mthr));
  }

  float m = mthr;
#pragma unroll
  for (int off = 32; off > 0; off >>= 1) {
    float ov = __shfl_xor(av, off);
    int   oi = __shfl_xor(ai, off);
    if (ov > av || (ov == av && oi < ai)) { av = ov; ai = oi; }
    float om = __shfl_xor(m, off);
    float os = __shfl_xor(s, off);
    float mn = fmaxf(m, om);
    s = fmaf(s, __expf(m - mn), os * __expf(om - mn));
    m = mn;
  }

  __shared__ float lds_av[AWAVES]; __shared__ int lds_ai[AWAVES];
  __shared__ float lds_m[AWAVES];  __shared__ float lds_s[AWAVES];
  const int wid = tid >> 6;
  if ((tid & 63) == 0) {
    lds_av[wid] = av; lds_ai[wid] = ai;
    lds_m[wid] = m;   lds_s[wid] = s;
  }
  __syncthreads();
  if (tid == 0) {
    float Av = lds_av[0]; int Ai = lds_ai[0];
    float M = lds_m[0];   float S = lds_s[0];
#pragma unroll
    for (int w = 1; w < AWAVES; ++w) {
      float ov = lds_av[w]; int oi = lds_ai[w];
      if (ov > Av || (ov == Av && oi < Ai)) { Av = ov; Ai = oi; }
      float om = lds_m[w]; float os = lds_s[w];
      float mn = fmaxf(M, om);
      S = fmaf(S, __expf(M - mn), os * __expf(om - mn));
      M = mn;
    }
    float* p = ws + (size_t)(b * CHUNKS + chunk) * G_STRIDE;
    p[0] = Av; p[1] = __int_as_float(Ai);
    p[2] = M;  p[3] = S;
  }
}

// ---------- K2: per-row merge -> constants (1 block, 256 threads) ----------
__global__ __launch_bounds__(B_ROWS) void fin1_kernel(
    const float* __restrict__ temps,
    float* __restrict__ ws) {
  const int r = threadIdx.x;
  const float t = temps[r];
  const float inv_t = (t == 0.0f) ? 1.0f : (1.0f / t);
  const float* p = ws + (size_t)r * CHUNKS * G_STRIDE;
  float Av = -INFINITY; int Ai = 0;
  float M = -INFINITY;  float S = 0.0f;
#pragma unroll
  for (int c = 0; c < CHUNKS; ++c) {
    const float* q = p + c * G_STRIDE;
    float ov = q[0]; int oi = __float_as_int(q[1]);
    if (ov > Av) { Av = ov; Ai = oi; }   // ascending chunks: first index wins
    float om = q[2]; float os = q[3];
    float mn = fmaxf(M, om);
    S = fmaf(S, __expf(M - mn), os * __expf(om - mn));
    M = mn;
  }
  float* f = ws + FIN_OFF + 8 * r;
  f[0] = -(M + __logf(S));          // cexp: probs = exp(fmaf(x, inv_t, cexp))
  f[1] = inv_t * LOG2E;             // a: rank scale
  f[2] = (M - GUMBEL_WINDOW_X) * t; // thrX: per-quad screen in raw-x units
  f[3] = M;                         // row max sx (chunk-level skip)
  f[4] = __int_as_float(Ai);        // greedy token
}

// ---------- K3: fused probs + screened gumbel ----------
__global__ __launch_bounds__(ATHREADS) void pass2_kernel(
    const float* __restrict__ logits,
    const float* __restrict__ temps,
    float* __restrict__ ws,
    float* __restrict__ out) {
  const uint32_t bx = blockIdx.x;
  const uint32_t b = bx / CHUNKS;
  const uint32_t chunk = bx - b * CHUNKS;
  const int tid = threadIdx.x;
  const float t = temps[b];
  const float inv_t = (t == 0.0f) ? 1.0f : (1.0f / t);
  const float* f = ws + FIN_OFF + 8 * b;
  const float cexp = f[0];
  const float a    = f[1];
  const float thrX = f[2];
  const float Mrow = f[3];
  const float myMc = ws[(size_t)(b * CHUNKS + chunk) * G_STRIDE + 2];

  const float* __restrict__ row = logits + (size_t)b * V_COLS;
  float* __restrict__ prow = out + B_ROWS + (size_t)b * V_COLS;
  const int q0 = (int)chunk * CHUNK_QUADS + tid;
  const int v0 = q0 * 4;
  const uint32_t cb42 = b * (uint32_t)V_COLS + (uint32_t)v0 + 42u;

  // block-uniform skip: t==0 row, or whole chunk provably can't win
  const bool doG = (t != 0.0f) && (myMc > Mrow - GUMBEL_WINDOW);

  if (doG) {
    float gv = -INFINITY; int gi = 0;
#pragma unroll
    for (int j = 0; j < QPT; ++j) {
      const float4 x4 = reinterpret_cast<const float4*>(row)[q0 + j * ATHREADS];
      float4 p4;
      p4.x = __expf(fmaf(x4.x, inv_t, cexp));
      p4.y = __expf(fmaf(x4.y, inv_t, cexp));
      p4.z = __expf(fmaf(x4.z, inv_t, cexp));
      p4.w = __expf(fmaf(x4.w, inv_t, cexp));
      reinterpret_cast<float4*>(prow)[q0 + j * ATHREADS] = p4;
      const float xa[4] = {x4.x, x4.y, x4.z, x4.w};
      const float mx4 = fmaxf(fmaxf(xa[0], xa[1]), fmaxf(xa[2], xa[3]));
      if (__any(mx4 > thrX)) {            // raw-x compare, no mul
#pragma unroll
        for (int k = 0; k < 4; ++k) {
          const float ll2 =
              gumbel_ll2(threefry_xor_pre(cb42 + (uint32_t)(j * 1024 + k)));
          const float c = fmaf(xa[k], a, -ll2);
          const bool up = c > gv;
          gv = up ? c : gv;
          gi = up ? (v0 + j * 1024 + k) : gi;
        }
      }
    }

#pragma unroll
    for (int off = 32; off > 0; off >>= 1) {
      float ov = __shfl_xor(gv, off);
      int   oi = __shfl_xor(gi, off);
      if (ov > gv || (ov == gv && oi < gi)) { gv = ov; gi = oi; }
    }

    __shared__ float lds_gv[AWAVES]; __shared__ int lds_gi[AWAVES];
    const int wid = tid >> 6;
    if ((tid & 63) == 0) { lds_gv[wid] = gv; lds_gi[wid] = gi; }
    __syncthreads();
    if (tid == 0) {
      float Gv = lds_gv[0]; int Gi = lds_gi[0];
#pragma unroll
      for (int w = 1; w < AWAVES; ++w) {
        float ov = lds_gv[w]; int oi = lds_gi[w];
        if (ov > Gv || (ov == Gv && oi < Gi)) { Gv = ov; Gi = oi; }
      }
      float* p = ws + S_OFF + (size_t)(b * CHUNKS + chunk) * 2;
      p[0] = Gv; p[1] = __int_as_float(Gi);
    }
  } else {
    // probs only (t==0 row, or chunk provably can't win the gumbel race)
#pragma unroll
    for (int j = 0; j < QPT; ++j) {
      const float4 x4 = reinterpret_cast<const float4*>(row)[q0 + j * ATHREADS];
      float4 p4;
      p4.x = __expf(fmaf(x4.x, inv_t, cexp));
      p4.y = __expf(fmaf(x4.y, inv_t, cexp));
      p4.z = __expf(fmaf(x4.z, inv_t, cexp));
      p4.w = __expf(fmaf(x4.w, inv_t, cexp));
      reinterpret_cast<float4*>(prow)[q0 + j * ATHREADS] = p4;
    }
    if (t != 0.0f && tid == 0) {
      float* p = ws + S_OFF + (size_t)(b * CHUNKS + chunk) * 2;
      p[0] = -INFINITY; p[1] = __int_as_float(0);   // sentinel
    }
  }
}

// ---------- K4: merge sample partials -> tokens ----------
__global__ __launch_bounds__(B_ROWS) void fin2_kernel(
    const float* __restrict__ temps,
    const float* __restrict__ ws,
    float* __restrict__ out) {
  const int r = threadIdx.x;
  const float t = temps[r];
  int token;
  if (t == 0.0f) {
    token = __float_as_int(ws[FIN_OFF + 8 * r + 4]);   // greedy
  } else {
    const float* sp = ws + S_OFF + (size_t)r * CHUNKS * 2;
    float Sv = -INFINITY; int Si = 0;
#pragma unroll
    for (int c = 0; c < CHUNKS; ++c) {
      float ov = sp[2 * c]; int oi = __float_as_int(sp[2 * c + 1]);
      if (ov > Sv) { Sv = ov; Si = oi; }   // ascending: first index wins
    }
    token = Si;
  }
  out[r] = (float)token;
}

extern "C" void kernel_launch(void* const* d_in, const int* in_sizes, int n_in,
                              void* d_out, int out_size, void* d_ws, size_t ws_size,
                              hipStream_t stream) {
  const float* logits = (const float*)d_in[0];
  const float* temps  = (const float*)d_in[1];
  float* out = (float*)d_out;
  float* ws  = (float*)d_ws;
  pass1_kernel<<<B_ROWS * CHUNKS, ATHREADS, 0, stream>>>(logits, temps, ws);
  fin1_kernel<<<1, B_ROWS, 0, stream>>>(temps, ws);
  pass2_kernel<<<B_ROWS * CHUNKS, ATHREADS, 0, stream>>>(logits, temps, ws, out);
  fin2_kernel<<<1, B_ROWS, 0, stream>>>(temps, ws, out);
}

// Round 15
// 99.281 us; speedup vs baseline: 1.1084x; 1.0283x over previous
//
#include <hip/hip_runtime.h>
#include <cstdint>
#include <cmath>

#define B_ROWS 256
#define V_COLS 128000
#define CHUNKS 25
#define CHUNK_QUADS 1280           // V_COLS/4/CHUNKS; exactly 5 quads/thread
#define ATHREADS 256
#define AWAVES 4
#define QPT 5
#define LOG2E 1.4426950408889634f
// gumbel span: u in [tiny, 1-2^-24] -> window ~20.4 sx-units. Chunk skip uses
// 21.2 (sx-units); per-quad screen threshold yThr precomputed in y-units with
// margin 21.4 (the extra 1.0 sx-unit ~ 1.44 y-units absorbs all round-trips).
#define GUMBEL_WINDOW 21.2f
#define GUMBEL_WINDOW_X 21.4f

// ws float layout:
//  G region: [row][chunk][4] = (Av, Ai, Mc, Sc)             @ 0,     25600
//  FIN:      [row][8] = (cexp2, a, yThr, Mrow, Ai, pad...)  @ 25600,  2048
//  S region: [row][chunk][2] = (Gv, Gi)                     @ 27648, 12800
#define G_STRIDE 4
#define FIN_OFF (B_ROWS * CHUNKS * G_STRIDE)
#define S_OFF (FIN_OFF + B_ROWS * 8)

__device__ __forceinline__ uint32_t rotl32(uint32_t x, uint32_t d) {
  return __builtin_amdgcn_alignbit(x, x, 32u - d);
}

// threefry2x32 key (0,42), XOR of outputs (JAX partitionable threefry).
// Caller pre-adds k1=42 into x1 (x0 = 0+k0 = 0): bit-identical stream.
__device__ __forceinline__ uint32_t threefry_xor_pre(uint32_t x1) {
  const uint32_t k1 = 42u;
  const uint32_t k2 = 0x1BD11BF0u;   // 0x1BD11BDA ^ 0 ^ 42
  uint32_t x0 = 0u;
#define TF_RND(r) { x0 += x1; x1 = rotl32(x1, (r)); x1 ^= x0; }
  TF_RND(13) TF_RND(15) TF_RND(26) TF_RND(6)
  x0 += k1; x1 += k2 + 1u;
  TF_RND(17) TF_RND(29) TF_RND(16) TF_RND(24)
  x0 += k2; x1 += 0u + 2u;
  TF_RND(13) TF_RND(15) TF_RND(26) TF_RND(6)
  x0 += 0u; x1 += k1 + 3u;
  TF_RND(17) TF_RND(29) TF_RND(16) TF_RND(24)
  x0 += k1; x1 += k2 + 4u;
  TF_RND(13) TF_RND(15) TF_RND(26) TF_RND(6)
  x0 += k2; x1 += 0u + 5u;
#undef TF_RND
  return x0 ^ x1;
}

// ll2 = log2(-log2(u)). Rank candidate c = y - ll2 where y is the probs
// exponent (row-uniform affine map of gumbel+sx => argmax-equivalent).
__device__ __forceinline__ float gumbel_ll2(uint32_t bits) {
  uint32_t ub = (bits >> 9) | 0x3f800000u;
  float f = __uint_as_float(ub) - 1.0f;
  float u = fmaxf(f, 1.17549435e-38f);
  const float l1 = __builtin_amdgcn_logf(u);     // log2(u), < 0
  return __builtin_amdgcn_logf(-l1);
}

// ---------- K1: softmax (Mc,Sc) + greedy argmax partials (no RNG) ----------
__global__ __launch_bounds__(ATHREADS) void pass1_kernel(
    const float* __restrict__ logits,
    const float* __restrict__ temps,
    float* __restrict__ ws) {
  const uint32_t bx = blockIdx.x;
  const uint32_t b = bx / CHUNKS;
  const uint32_t chunk = bx - b * CHUNKS;
  const int tid = threadIdx.x;
  const float t = temps[b];
  const float inv_t = (t == 0.0f) ? 1.0f : (1.0f / t);
  const float* __restrict__ row = logits + (size_t)b * V_COLS;
  const int q0 = (int)chunk * CHUNK_QUADS + tid;

  float4 xq[QPT];
#pragma unroll
  for (int j = 0; j < QPT; ++j)
    xq[j] = reinterpret_cast<const float4*>(row)[q0 + j * ATHREADS];

  // greedy argmax over raw x; strict > + ascending order => first index wins
  float av = -INFINITY; int ai = 0;
  const int v0 = q0 * 4;
#pragma unroll
  for (int j = 0; j < QPT; ++j) {
    const float xa[4] = {xq[j].x, xq[j].y, xq[j].z, xq[j].w};
#pragma unroll
    for (int k = 0; k < 4; ++k) {
      const bool up = xa[k] > av;
      av = up ? xa[k] : av;
      ai = up ? (v0 + j * 1024 + k) : ai;
    }
  }

  // thread max of sx bitwise (mul by inv_t>0 is round-monotone)
  const float mthr = av * inv_t;
  float s = 0.0f;
#pragma unroll
  for (int j = 0; j < QPT; ++j) {
    s += __expf(fmaf(xq[j].x, inv_t, -mthr));
    s += __expf(fmaf(xq[j].y, inv_t, -mthr));
    s += __expf(fmaf(xq[j].z, inv_t, -mthr));
    s += __expf(fmaf(xq[j].w, inv_t, -mthr));
  }

  float m = mthr;
#pragma unroll
  for (int off = 32; off > 0; off >>= 1) {
    float ov = __shfl_xor(av, off);
    int   oi = __shfl_xor(ai, off);
    if (ov > av || (ov == av && oi < ai)) { av = ov; ai = oi; }
    float om = __shfl_xor(m, off);
    float os = __shfl_xor(s, off);
    float mn = fmaxf(m, om);
    s = fmaf(s, __expf(m - mn), os * __expf(om - mn));
    m = mn;
  }

  __shared__ float lds_av[AWAVES]; __shared__ int lds_ai[AWAVES];
  __shared__ float lds_m[AWAVES];  __shared__ float lds_s[AWAVES];
  const int wid = tid >> 6;
  if ((tid & 63) == 0) {
    lds_av[wid] = av; lds_ai[wid] = ai;
    lds_m[wid] = m;   lds_s[wid] = s;
  }
  __syncthreads();
  if (tid == 0) {
    float Av = lds_av[0]; int Ai = lds_ai[0];
    float M = lds_m[0];   float S = lds_s[0];
#pragma unroll
    for (int w = 1; w < AWAVES; ++w) {
      float ov = lds_av[w]; int oi = lds_ai[w];
      if (ov > Av || (ov == Av && oi < Ai)) { Av = ov; Ai = oi; }
      float om = lds_m[w]; float os = lds_s[w];
      float mn = fmaxf(M, om);
      S = fmaf(S, __expf(M - mn), os * __expf(om - mn));
      M = mn;
    }
    float* p = ws + (size_t)(b * CHUNKS + chunk) * G_STRIDE;
    p[0] = Av; p[1] = __int_as_float(Ai);
    p[2] = M;  p[3] = S;
  }
}

// ---------- K2: per-row merge -> constants (1 block, 256 threads) ----------
__global__ __launch_bounds__(B_ROWS) void fin1_kernel(
    const float* __restrict__ temps,
    float* __restrict__ ws) {
  const int r = threadIdx.x;
  const float t = temps[r];
  const float inv_t = (t == 0.0f) ? 1.0f : (1.0f / t);
  const float* p = ws + (size_t)r * CHUNKS * G_STRIDE;
  float Av = -INFINITY; int Ai = 0;
  float M = -INFINITY;  float S = 0.0f;
#pragma unroll
  for (int c = 0; c < CHUNKS; ++c) {
    const float* q = p + c * G_STRIDE;
    float ov = q[0]; int oi = __float_as_int(q[1]);
    if (ov > Av) { Av = ov; Ai = oi; }   // ascending chunks: first index wins
    float om = q[2]; float os = q[3];
    float mn = fmaxf(M, om);
    S = fmaf(S, __expf(M - mn), os * __expf(om - mn));
    M = mn;
  }
  const float a = inv_t * LOG2E;
  const float cexp2 = -(M + __logf(S)) * LOG2E; // probs = exp2(fma(x,a,cexp2))
  const float thrX = (M - GUMBEL_WINDOW_X) * t; // screen threshold, raw-x
  float* f = ws + FIN_OFF + 8 * r;
  f[0] = cexp2;
  f[1] = a;
  f[2] = fmaf(thrX, a, cexp2);      // yThr: screen in y-units (monotone in x)
  f[3] = M;                         // row max sx (chunk-level skip)
  f[4] = __int_as_float(Ai);        // greedy token
}

// ---------- K3: fused probs + screened gumbel (y-domain rank) ----------
__global__ __launch_bounds__(ATHREADS) void pass2_kernel(
    const float* __restrict__ logits,
    const float* __restrict__ temps,
    float* __restrict__ ws,
    float* __restrict__ out) {
  const uint32_t bx = blockIdx.x;
  const uint32_t b = bx / CHUNKS;
  const uint32_t chunk = bx - b * CHUNKS;
  const int tid = threadIdx.x;
  const float t = temps[b];
  const float* f = ws + FIN_OFF + 8 * b;
  const float cexp2 = f[0];
  const float a     = f[1];
  const float yThr  = f[2];
  const float Mrow  = f[3];
  const float myMc = ws[(size_t)(b * CHUNKS + chunk) * G_STRIDE + 2];

  const float* __restrict__ row = logits + (size_t)b * V_COLS;
  float* __restrict__ prow = out + B_ROWS + (size_t)b * V_COLS;
  const int q0 = (int)chunk * CHUNK_QUADS + tid;
  const int v0 = q0 * 4;
  const uint32_t cb42 = b * (uint32_t)V_COLS + (uint32_t)v0 + 42u;

  // block-uniform skip: t==0 row, or whole chunk provably can't win
  const bool doG = (t != 0.0f) && (myMc > Mrow - GUMBEL_WINDOW);

  if (doG) {
    float gv = -INFINITY; int giRel = 0;
#pragma unroll
    for (int j = 0; j < QPT; ++j) {
      const float4 x4 = reinterpret_cast<const float4*>(row)[q0 + j * ATHREADS];
      // probs exponents (y) + native exp2
      const float y0 = fmaf(x4.x, a, cexp2);
      const float y1 = fmaf(x4.y, a, cexp2);
      const float y2 = fmaf(x4.z, a, cexp2);
      const float y3 = fmaf(x4.w, a, cexp2);
      float4 p4;
      p4.x = __builtin_amdgcn_exp2f(y0);
      p4.y = __builtin_amdgcn_exp2f(y1);
      p4.z = __builtin_amdgcn_exp2f(y2);
      p4.w = __builtin_amdgcn_exp2f(y3);
      reinterpret_cast<float4*>(prow)[q0 + j * ATHREADS] = p4;
      // screen in y-space (monotone in x); rank c = y - ll2
      const float ymax4 = fmaxf(fmaxf(y0, y1), fmaxf(y2, y3));
      if (__any(ymax4 > yThr)) {
        const float ya[4] = {y0, y1, y2, y3};
#pragma unroll
        for (int k = 0; k < 4; ++k) {
          const float ll2 =
              gumbel_ll2(threefry_xor_pre(cb42 + (uint32_t)(j * 1024 + k)));
          const float c = ya[k] - ll2;
          const bool up = c > gv;
          gv = up ? c : gv;
          giRel = up ? (j * 1024 + k) : giRel;   // literal src0 cndmask
        }
      }
    }
    int gi = v0 + giRel;

#pragma unroll
    for (int off = 32; off > 0; off >>= 1) {
      float ov = __shfl_xor(gv, off);
      int   oi = __shfl_xor(gi, off);
      if (ov > gv || (ov == gv && oi < gi)) { gv = ov; gi = oi; }
    }

    __shared__ float lds_gv[AWAVES]; __shared__ int lds_gi[AWAVES];
    const int wid = tid >> 6;
    if ((tid & 63) == 0) { lds_gv[wid] = gv; lds_gi[wid] = gi; }
    __syncthreads();
    if (tid == 0) {
      float Gv = lds_gv[0]; int Gi = lds_gi[0];
#pragma unroll
      for (int w = 1; w < AWAVES; ++w) {
        float ov = lds_gv[w]; int oi = lds_gi[w];
        if (ov > Gv || (ov == Gv && oi < Gi)) { Gv = ov; Gi = oi; }
      }
      float* p = ws + S_OFF + (size_t)(b * CHUNKS + chunk) * 2;
      p[0] = Gv; p[1] = __int_as_float(Gi);
    }
  } else {
    // probs only (t==0 row, or chunk provably can't win the gumbel race)
#pragma unroll
    for (int j = 0; j < QPT; ++j) {
      const float4 x4 = reinterpret_cast<const float4*>(row)[q0 + j * ATHREADS];
      float4 p4;
      p4.x = __builtin_amdgcn_exp2f(fmaf(x4.x, a, cexp2));
      p4.y = __builtin_amdgcn_exp2f(fmaf(x4.y, a, cexp2));
      p4.z = __builtin_amdgcn_exp2f(fmaf(x4.z, a, cexp2));
      p4.w = __builtin_amdgcn_exp2f(fmaf(x4.w, a, cexp2));
      reinterpret_cast<float4*>(prow)[q0 + j * ATHREADS] = p4;
    }
    if (t != 0.0f && tid == 0) {
      float* p = ws + S_OFF + (size_t)(b * CHUNKS + chunk) * 2;
      p[0] = -INFINITY; p[1] = __int_as_float(0);   // sentinel
    }
  }
}

// ---------- K4: merge sample partials -> tokens ----------
__global__ __launch_bounds__(B_ROWS) void fin2_kernel(
    const float* __restrict__ temps,
    const float* __restrict__ ws,
    float* __restrict__ out) {
  const int r = threadIdx.x;
  const float t = temps[r];
  int token;
  if (t == 0.0f) {
    token = __float_as_int(ws[FIN_OFF + 8 * r + 4]);   // greedy
  } else {
    const float* sp = ws + S_OFF + (size_t)r * CHUNKS * 2;
    float Sv = -INFINITY; int Si = 0;
#pragma unroll
    for (int c = 0; c < CHUNKS; ++c) {
      float ov = sp[2 * c]; int oi = __float_as_int(sp[2 * c + 1]);
      if (ov > Sv) { Sv = ov; Si = oi; }   // ascending: first index wins
    }
    token = Si;
  }
  out[r] = (float)token;
}

extern "C" void kernel_launch(void* const* d_in, const int* in_sizes, int n_in,
                              void* d_out, int out_size, void* d_ws, size_t ws_size,
                              hipStream_t stream) {
  const float* logits = (const float*)d_in[0];
  const float* temps  = (const float*)d_in[1];
  float* out = (float*)d_out;
  float* ws  = (float*)d_ws;
  pass1_kernel<<<B_ROWS * CHUNKS, ATHREADS, 0, stream>>>(logits, temps, ws);
  fin1_kernel<<<1, B_ROWS, 0, stream>>>(temps, ws);
  pass2_kernel<<<B_ROWS * CHUNKS, ATHREADS, 0, stream>>>(logits, temps, ws, out);
  fin2_kernel<<<1, B_ROWS, 0, stream>>>(temps, ws, out);
}